// Round 3
// baseline (326.475 us; speedup 1.0000x reference)
//
#include <hip/hip_runtime.h>

// ---------------- CSR build kernels ----------------

__global__ void k_zero(int* __restrict__ deg, int n) {
    int i = blockIdx.x * 256 + threadIdx.x;
    if (i < n) deg[i] = 0;
}

__global__ void k_count(const int* __restrict__ dst, int* __restrict__ deg, int e) {
    int i = blockIdx.x * 256 + threadIdx.x;
    if (i < e) atomicAdd(&deg[dst[i]], 1);
}

__global__ void k_inv(const int* __restrict__ deg, float* __restrict__ inv, int n) {
    int i = blockIdx.x * 256 + threadIdx.x;
    if (i < n) inv[i] = rsqrtf((float)deg[i] + 1.0f);
}

// block-level exclusive scan (256/block), emits per-block total
__global__ void k_scan1(const int* __restrict__ deg, int* __restrict__ rowstart,
                        int* __restrict__ blocksum, int n) {
    __shared__ int s[256];
    int tid = threadIdx.x;
    int gid = blockIdx.x * 256 + tid;
    int v = (gid < n) ? deg[gid] : 0;
    s[tid] = v;
    __syncthreads();
    for (int off = 1; off < 256; off <<= 1) {
        int t = (tid >= off) ? s[tid - off] : 0;
        __syncthreads();
        s[tid] += t;
        __syncthreads();
    }
    if (gid < n) rowstart[gid] = s[tid] - v;   // exclusive
    if (tid == 255) blocksum[blockIdx.x] = s[255];
}

// scan the block sums (nb <= 256), in-place exclusive
__global__ void k_scan2(int* __restrict__ bs, int nb) {
    __shared__ int s[256];
    int tid = threadIdx.x;
    int v = (tid < nb) ? bs[tid] : 0;
    s[tid] = v;
    __syncthreads();
    for (int off = 1; off < 256; off <<= 1) {
        int t = (tid >= off) ? s[tid - off] : 0;
        __syncthreads();
        s[tid] += t;
        __syncthreads();
    }
    if (tid < nb) bs[tid] = s[tid] - v;        // exclusive block offsets
}

__global__ void k_scan3(int* __restrict__ rowstart, const int* __restrict__ boff,
                        int* __restrict__ cursor, int n, int e) {
    int i = blockIdx.x * 256 + threadIdx.x;
    if (i < n) {
        int r = rowstart[i] + boff[blockIdx.x];
        rowstart[i] = r;
        cursor[i] = r;
    }
    if (i == 0) rowstart[n] = e;
}

__global__ void k_fill(const int* __restrict__ src, const int* __restrict__ dst,
                       const float* __restrict__ inv, int* __restrict__ cursor,
                       int* __restrict__ ssrc, float* __restrict__ sw, int e) {
    int i = blockIdx.x * 256 + threadIdx.x;
    if (i < e) {
        int d = dst[i];
        int s = src[i];
        int p = atomicAdd(&cursor[d], 1);
        ssrc[p] = s;
        sw[p] = inv[s];
    }
}

// ---------------- GEMM kernels (fp32, vector ALU) ----------------

// h[n,128] = x[n,128] @ W[128,128]; 32 rows per block, full W in LDS.
__global__ __launch_bounds__(256) void k_gemm1(const float* __restrict__ x,
                                               const float* __restrict__ W,
                                               float* __restrict__ h, int n) {
    __shared__ float sW[128 * 128];   // 64 KiB
    __shared__ float sx[32 * 128];    // 16 KiB
    int tid = threadIdx.x;
    for (int i = tid * 4; i < 128 * 128; i += 1024)
        *(float4*)&sW[i] = *(const float4*)&W[i];
    int row0 = blockIdx.x * 32;
    for (int i = tid * 4; i < 32 * 128; i += 1024) {
        int r = row0 + (i >> 7);
        float4 v = (r < n) ? *(const float4*)&x[r * 128 + (i & 127)]
                           : make_float4(0.f, 0.f, 0.f, 0.f);
        *(float4*)&sx[i] = v;
    }
    __syncthreads();
    int c4 = (tid & 31) * 4;   // 32 col-groups x 4 cols = 128 cols
    int rg = tid >> 5;         // 8 row-groups; rows rg + 8*i
    float4 acc[4] = {};
    #pragma unroll 4
    for (int k = 0; k < 128; ++k) {
        float4 wv = *(const float4*)&sW[k * 128 + c4];
        #pragma unroll
        for (int i = 0; i < 4; ++i) {
            float xv = sx[(rg + 8 * i) * 128 + k];
            acc[i].x += xv * wv.x; acc[i].y += xv * wv.y;
            acc[i].z += xv * wv.z; acc[i].w += xv * wv.w;
        }
    }
    #pragma unroll
    for (int i = 0; i < 4; ++i) {
        int r = row0 + rg + 8 * i;
        if (r < n) *(float4*)&h[r * 128 + c4] = acc[i];
    }
}

// h[n,64] = a[n,128] @ W[128,64]; 64 rows per block.
__global__ __launch_bounds__(256) void k_gemm2(const float* __restrict__ a,
                                               const float* __restrict__ W,
                                               float* __restrict__ h, int n) {
    __shared__ float sW[128 * 64];    // 32 KiB
    __shared__ float sx[64 * 128];    // 32 KiB
    int tid = threadIdx.x;
    for (int i = tid * 4; i < 128 * 64; i += 1024)
        *(float4*)&sW[i] = *(const float4*)&W[i];
    int row0 = blockIdx.x * 64;
    for (int i = tid * 4; i < 64 * 128; i += 1024) {
        int r = row0 + (i >> 7);
        float4 v = (r < n) ? *(const float4*)&a[r * 128 + (i & 127)]
                           : make_float4(0.f, 0.f, 0.f, 0.f);
        *(float4*)&sx[i] = v;
    }
    __syncthreads();
    int c4 = (tid & 15) * 4;   // 16 col-groups x 4 = 64 cols
    int rg = tid >> 4;         // 16 row-groups; rows rg + 16*i
    float4 acc[4] = {};
    #pragma unroll 4
    for (int k = 0; k < 128; ++k) {
        float4 wv = *(const float4*)&sW[k * 64 + c4];
        #pragma unroll
        for (int i = 0; i < 4; ++i) {
            float xv = sx[(rg + 16 * i) * 128 + k];
            acc[i].x += xv * wv.x; acc[i].y += xv * wv.y;
            acc[i].z += xv * wv.z; acc[i].w += xv * wv.w;
        }
    }
    #pragma unroll
    for (int i = 0; i < 4; ++i) {
        int r = row0 + rg + 16 * i;
        if (r < n) *(float4*)&h[r * 64 + c4] = acc[i];
    }
}

// ---------------- Gather (aggregation) ----------------
// One wave per destination node. COLS=128: float2/lane; COLS=64: float/lane.
template <int COLS, bool RELU>
__global__ __launch_bounds__(256) void k_gather(const float* __restrict__ h,
                                                const int* __restrict__ rowstart,
                                                const int* __restrict__ ssrc,
                                                const float* __restrict__ sw,
                                                const float* __restrict__ inv,
                                                const float* __restrict__ bias,
                                                float* __restrict__ out, int n) {
    int wave = threadIdx.x >> 6;
    int lane = threadIdx.x & 63;
    int node = blockIdx.x * 4 + wave;
    if (node >= n) return;
    int s0 = rowstart[node];
    int s1 = rowstart[node + 1];
    float iv = inv[node];

    if constexpr (COLS == 128) {
        int c = lane * 2;
        float accx = 0.f, accy = 0.f;
        int i = s0;
        for (; i + 4 <= s1; i += 4) {
            int a0 = ssrc[i], a1 = ssrc[i + 1], a2 = ssrc[i + 2], a3 = ssrc[i + 3];
            float w0 = sw[i], w1 = sw[i + 1], w2 = sw[i + 2], w3 = sw[i + 3];
            float2 v0 = *(const float2*)&h[a0 * 128 + c];
            float2 v1 = *(const float2*)&h[a1 * 128 + c];
            float2 v2 = *(const float2*)&h[a2 * 128 + c];
            float2 v3 = *(const float2*)&h[a3 * 128 + c];
            accx += w0 * v0.x + w1 * v1.x + w2 * v2.x + w3 * v3.x;
            accy += w0 * v0.y + w1 * v1.y + w2 * v2.y + w3 * v3.y;
        }
        for (; i < s1; ++i) {
            int a0 = ssrc[i];
            float w0 = sw[i];
            float2 v0 = *(const float2*)&h[a0 * 128 + c];
            accx += w0 * v0.x;
            accy += w0 * v0.y;
        }
        float2 self = *(const float2*)&h[node * 128 + c];
        float2 bb = *(const float2*)&bias[c];
        float ox = iv * accx + iv * iv * self.x + bb.x;
        float oy = iv * accy + iv * iv * self.y + bb.y;
        if (RELU) { ox = fmaxf(ox, 0.f); oy = fmaxf(oy, 0.f); }
        *(float2*)&out[node * 128 + c] = make_float2(ox, oy);
    } else {
        int c = lane;
        float acc = 0.f;
        int i = s0;
        for (; i + 4 <= s1; i += 4) {
            int a0 = ssrc[i], a1 = ssrc[i + 1], a2 = ssrc[i + 2], a3 = ssrc[i + 3];
            float w0 = sw[i], w1 = sw[i + 1], w2 = sw[i + 2], w3 = sw[i + 3];
            acc += w0 * h[a0 * 64 + c] + w1 * h[a1 * 64 + c] +
                   w2 * h[a2 * 64 + c] + w3 * h[a3 * 64 + c];
        }
        for (; i < s1; ++i) acc += sw[i] * h[ssrc[i] * 64 + c];
        float o = iv * acc + iv * iv * h[node * 64 + c] + bias[c];
        if (RELU) o = fmaxf(o, 0.f);
        out[node * 64 + c] = o;
    }
}

// ---------------- launcher ----------------

extern "C" void kernel_launch(void* const* d_in, const int* in_sizes, int n_in,
                              void* d_out, int out_size, void* d_ws, size_t ws_size,
                              hipStream_t stream) {
    const float* x  = (const float*)d_in[0];
    const int*   ei = (const int*)d_in[1];
    const float* W1 = (const float*)d_in[2];
    const float* b1 = (const float*)d_in[3];
    const float* W2 = (const float*)d_in[4];
    const float* b2 = (const float*)d_in[5];
    float* out = (float*)d_out;

    const int N = in_sizes[0] / 128;   // 50000
    const int E = in_sizes[1] / 2;     // 800000
    const int* src = ei;
    const int* dstp = ei + E;

    char* p = (char*)d_ws;
    auto take = [&](size_t bytes) {
        char* r = p;
        p += (bytes + 255) & ~(size_t)255;
        return r;
    };
    int*   deg      = (int*)take((size_t)N * 4);
    float* inv      = (float*)take((size_t)N * 4);
    int*   rowstart = (int*)take((size_t)(N + 1) * 4);
    int*   cursor   = (int*)take((size_t)N * 4);
    int*   blocksum = (int*)take(256 * 4);
    int*   ssrc     = (int*)take((size_t)E * 4);
    float* swv      = (float*)take((size_t)E * 4);
    float* h1       = (float*)take((size_t)N * 128 * 4);
    float* act1     = (float*)take((size_t)N * 128 * 4);
    float* h2       = h1;   // h1 dead after gather-1

    const int nbN = (N + 255) / 256;   // 196 (<=256, fits single-block scan2)
    const int nbE = (E + 255) / 256;

    k_zero<<<nbN, 256, 0, stream>>>(deg, N);
    k_count<<<nbE, 256, 0, stream>>>(dstp, deg, E);
    k_inv<<<nbN, 256, 0, stream>>>(deg, inv, N);
    k_scan1<<<nbN, 256, 0, stream>>>(deg, rowstart, blocksum, N);
    k_scan2<<<1, 256, 0, stream>>>(blocksum, nbN);
    k_scan3<<<nbN, 256, 0, stream>>>(rowstart, blocksum, cursor, N, E);
    k_fill<<<nbE, 256, 0, stream>>>(src, dstp, inv, cursor, ssrc, swv, E);

    k_gemm1<<<(N + 31) / 32, 256, 0, stream>>>(x, W1, h1, N);
    k_gather<128, true><<<(N + 3) / 4, 256, 0, stream>>>(h1, rowstart, ssrc, swv, inv, b1, act1, N);
    k_gemm2<<<(N + 63) / 64, 256, 0, stream>>>(act1, W2, h2, N);
    k_gather<64, false><<<(N + 3) / 4, 256, 0, stream>>>(h2, rowstart, ssrc, swv, inv, b2, out, N);
}

// Round 4
// 312.338 us; speedup vs baseline: 1.0453x; 1.0453x over previous
//
#include <hip/hip_runtime.h>

typedef unsigned int uint32;
typedef unsigned short ushort16;

__device__ __forceinline__ ushort16 f2bf(float f) {
    union { float f; uint32 u; } v; v.f = f;
    uint32 r = v.u + 0x7fffu + ((v.u >> 16) & 1u);   // RNE
    return (ushort16)(r >> 16);
}
__device__ __forceinline__ float bflo(uint32 u) {            // low ushort -> f32
    union { uint32 u; float f; } v; v.u = u << 16; return v.f;
}
__device__ __forceinline__ float bfhi(uint32 u) {            // high ushort -> f32
    union { uint32 u; float f; } v; v.u = u & 0xffff0000u; return v.f;
}

// ---------------- CSR build kernels ----------------

__global__ void k_zero(int* __restrict__ deg, int n) {
    int i = blockIdx.x * 256 + threadIdx.x;
    if (i < n) deg[i] = 0;
}

__global__ void k_count(const int* __restrict__ dst, int* __restrict__ deg, int e) {
    int i = blockIdx.x * 256 + threadIdx.x;
    if (i < e) atomicAdd(&deg[dst[i]], 1);
}

__global__ void k_inv(const int* __restrict__ deg, float* __restrict__ inv, int n) {
    int i = blockIdx.x * 256 + threadIdx.x;
    if (i < n) inv[i] = rsqrtf((float)deg[i] + 1.0f);
}

__global__ void k_scan1(const int* __restrict__ deg, int* __restrict__ rowstart,
                        int* __restrict__ blocksum, int n) {
    __shared__ int s[256];
    int tid = threadIdx.x;
    int gid = blockIdx.x * 256 + tid;
    int v = (gid < n) ? deg[gid] : 0;
    s[tid] = v;
    __syncthreads();
    for (int off = 1; off < 256; off <<= 1) {
        int t = (tid >= off) ? s[tid - off] : 0;
        __syncthreads();
        s[tid] += t;
        __syncthreads();
    }
    if (gid < n) rowstart[gid] = s[tid] - v;   // exclusive
    if (tid == 255) blocksum[blockIdx.x] = s[255];
}

__global__ void k_scan2(int* __restrict__ bs, int nb) {
    __shared__ int s[256];
    int tid = threadIdx.x;
    int v = (tid < nb) ? bs[tid] : 0;
    s[tid] = v;
    __syncthreads();
    for (int off = 1; off < 256; off <<= 1) {
        int t = (tid >= off) ? s[tid - off] : 0;
        __syncthreads();
        s[tid] += t;
        __syncthreads();
    }
    if (tid < nb) bs[tid] = s[tid] - v;        // exclusive block offsets
}

__global__ void k_scan3(int* __restrict__ rowstart, const int* __restrict__ boff,
                        int* __restrict__ cursor, int n, int e) {
    int i = blockIdx.x * 256 + threadIdx.x;
    if (i < n) {
        int r = rowstart[i] + boff[blockIdx.x];
        rowstart[i] = r;
        cursor[i] = r;
    }
    if (i == 0) rowstart[n] = e;
}

__global__ void k_fill(const int* __restrict__ src, const int* __restrict__ dst,
                       const float* __restrict__ inv, int* __restrict__ cursor,
                       int* __restrict__ ssrc, float* __restrict__ sw, int e) {
    int i = blockIdx.x * 256 + threadIdx.x;
    if (i < e) {
        int d = dst[i];
        int s = src[i];
        int p = atomicAdd(&cursor[d], 1);
        ssrc[p] = s;
        sw[p] = inv[s];
    }
}

// ---------------- GEMM kernels (fp32 compute, bf16 output) ----------------

// h[n,128](bf16) = x[n,128] @ W[128,128]; 32 rows/block, full W in LDS.
__global__ __launch_bounds__(256) void k_gemm1(const float* __restrict__ x,
                                               const float* __restrict__ W,
                                               ushort16* __restrict__ h, int n) {
    __shared__ float sW[128 * 128];   // 64 KiB
    __shared__ float sx[32 * 128];    // 16 KiB
    int tid = threadIdx.x;
    for (int i = tid * 4; i < 128 * 128; i += 1024)
        *(float4*)&sW[i] = *(const float4*)&W[i];
    int row0 = blockIdx.x * 32;
    for (int i = tid * 4; i < 32 * 128; i += 1024) {
        int r = row0 + (i >> 7);
        float4 v = (r < n) ? *(const float4*)&x[r * 128 + (i & 127)]
                           : make_float4(0.f, 0.f, 0.f, 0.f);
        *(float4*)&sx[i] = v;
    }
    __syncthreads();
    int c4 = (tid & 31) * 4;
    int rg = tid >> 5;
    float4 acc[4] = {};
    #pragma unroll 4
    for (int k = 0; k < 128; ++k) {
        float4 wv = *(const float4*)&sW[k * 128 + c4];
        #pragma unroll
        for (int i = 0; i < 4; ++i) {
            float xv = sx[(rg + 8 * i) * 128 + k];
            acc[i].x += xv * wv.x; acc[i].y += xv * wv.y;
            acc[i].z += xv * wv.z; acc[i].w += xv * wv.w;
        }
    }
    #pragma unroll
    for (int i = 0; i < 4; ++i) {
        int r = row0 + rg + 8 * i;
        if (r < n) {
            uint32 lo = (uint32)f2bf(acc[i].x) | ((uint32)f2bf(acc[i].y) << 16);
            uint32 hi = (uint32)f2bf(acc[i].z) | ((uint32)f2bf(acc[i].w) << 16);
            *(uint2*)&h[r * 128 + c4] = make_uint2(lo, hi);
        }
    }
}

// h[n,64](bf16) = a[n,128] @ W[128,64]; 64 rows/block.
__global__ __launch_bounds__(256) void k_gemm2(const float* __restrict__ a,
                                               const float* __restrict__ W,
                                               ushort16* __restrict__ h, int n) {
    __shared__ float sW[128 * 64];    // 32 KiB
    __shared__ float sx[64 * 128];    // 32 KiB
    int tid = threadIdx.x;
    for (int i = tid * 4; i < 128 * 64; i += 1024)
        *(float4*)&sW[i] = *(const float4*)&W[i];
    int row0 = blockIdx.x * 64;
    for (int i = tid * 4; i < 64 * 128; i += 1024) {
        int r = row0 + (i >> 7);
        float4 v = (r < n) ? *(const float4*)&a[r * 128 + (i & 127)]
                           : make_float4(0.f, 0.f, 0.f, 0.f);
        *(float4*)&sx[i] = v;
    }
    __syncthreads();
    int c4 = (tid & 15) * 4;
    int rg = tid >> 4;
    float4 acc[4] = {};
    #pragma unroll 4
    for (int k = 0; k < 128; ++k) {
        float4 wv = *(const float4*)&sW[k * 64 + c4];
        #pragma unroll
        for (int i = 0; i < 4; ++i) {
            float xv = sx[(rg + 16 * i) * 128 + k];
            acc[i].x += xv * wv.x; acc[i].y += xv * wv.y;
            acc[i].z += xv * wv.z; acc[i].w += xv * wv.w;
        }
    }
    #pragma unroll
    for (int i = 0; i < 4; ++i) {
        int r = row0 + rg + 16 * i;
        if (r < n) {
            uint32 lo = (uint32)f2bf(acc[i].x) | ((uint32)f2bf(acc[i].y) << 16);
            uint32 hi = (uint32)f2bf(acc[i].z) | ((uint32)f2bf(acc[i].w) << 16);
            *(uint2*)&h[r * 64 + c4] = make_uint2(lo, hi);
        }
    }
}

// ---------------- Gather (aggregation), bf16 source rows ----------------
// One wave per destination node.
// COLS=128: lane covers 2 cols via one dword load. COLS=64: lane covers 1 col (ushort).
template <int COLS, bool RELU>
__global__ __launch_bounds__(256) void k_gather(const ushort16* __restrict__ h,
                                                const int* __restrict__ rowstart,
                                                const int* __restrict__ ssrc,
                                                const float* __restrict__ sw,
                                                const float* __restrict__ inv,
                                                const float* __restrict__ bias,
                                                float* __restrict__ out, int n) {
    int wave = threadIdx.x >> 6;
    int lane = threadIdx.x & 63;
    int node = blockIdx.x * 4 + wave;
    if (node >= n) return;
    int s0 = rowstart[node];
    int s1 = rowstart[node + 1];
    float iv = inv[node];

    if constexpr (COLS == 128) {
        int c = lane * 2;
        float accx = 0.f, accy = 0.f;
        int i = s0;
        for (; i + 8 <= s1; i += 8) {
            int   a[8];
            float w[8];
            uint32 u[8];
            #pragma unroll
            for (int j = 0; j < 8; ++j) { a[j] = ssrc[i + j]; w[j] = sw[i + j]; }
            #pragma unroll
            for (int j = 0; j < 8; ++j)
                u[j] = *(const uint32*)&h[(size_t)a[j] * 128 + c];
            #pragma unroll
            for (int j = 0; j < 8; ++j) {
                accx += w[j] * bflo(u[j]);
                accy += w[j] * bfhi(u[j]);
            }
        }
        for (; i < s1; ++i) {
            uint32 u = *(const uint32*)&h[(size_t)ssrc[i] * 128 + c];
            float w = sw[i];
            accx += w * bflo(u);
            accy += w * bfhi(u);
        }
        uint32 us = *(const uint32*)&h[(size_t)node * 128 + c];
        float2 bb = *(const float2*)&bias[c];
        float ox = iv * accx + iv * iv * bflo(us) + bb.x;
        float oy = iv * accy + iv * iv * bfhi(us) + bb.y;
        if (RELU) { ox = fmaxf(ox, 0.f); oy = fmaxf(oy, 0.f); }
        *(float2*)&out[node * 128 + c] = make_float2(ox, oy);
    } else {
        int c = lane;
        float acc = 0.f;
        int i = s0;
        for (; i + 8 <= s1; i += 8) {
            int   a[8];
            float w[8];
            ushort16 u[8];
            #pragma unroll
            for (int j = 0; j < 8; ++j) { a[j] = ssrc[i + j]; w[j] = sw[i + j]; }
            #pragma unroll
            for (int j = 0; j < 8; ++j)
                u[j] = h[(size_t)a[j] * 64 + c];
            #pragma unroll
            for (int j = 0; j < 8; ++j)
                acc += w[j] * bflo((uint32)u[j]);
        }
        for (; i < s1; ++i)
            acc += sw[i] * bflo((uint32)h[(size_t)ssrc[i] * 64 + c]);
        float self = bflo((uint32)h[(size_t)node * 64 + c]);
        float o = iv * acc + iv * iv * self + bias[c];
        if (RELU) o = fmaxf(o, 0.f);
        out[node * 64 + c] = o;
    }
}

// ---------------- launcher ----------------

extern "C" void kernel_launch(void* const* d_in, const int* in_sizes, int n_in,
                              void* d_out, int out_size, void* d_ws, size_t ws_size,
                              hipStream_t stream) {
    const float* x  = (const float*)d_in[0];
    const int*   ei = (const int*)d_in[1];
    const float* W1 = (const float*)d_in[2];
    const float* b1 = (const float*)d_in[3];
    const float* W2 = (const float*)d_in[4];
    const float* b2 = (const float*)d_in[5];
    float* out = (float*)d_out;

    const int N = in_sizes[0] / 128;   // 50000
    const int E = in_sizes[1] / 2;     // 800000
    const int* src = ei;
    const int* dstp = ei + E;

    char* p = (char*)d_ws;
    auto take = [&](size_t bytes) {
        char* r = p;
        p += (bytes + 255) & ~(size_t)255;
        return r;
    };
    int*      deg      = (int*)take((size_t)N * 4);
    float*    inv      = (float*)take((size_t)N * 4);
    int*      rowstart = (int*)take((size_t)(N + 1) * 4);
    int*      cursor   = (int*)take((size_t)N * 4);
    int*      blocksum = (int*)take(256 * 4);
    int*      ssrc     = (int*)take((size_t)E * 4);
    float*    swv      = (float*)take((size_t)E * 4);
    ushort16* h1       = (ushort16*)take((size_t)N * 128 * 2);  // bf16
    float*    act1     = (float*)take((size_t)N * 128 * 4);     // fp32
    ushort16* h2       = (ushort16*)h1;  // bf16, h1 dead after gather-1

    const int nbN = (N + 255) / 256;
    const int nbE = (E + 255) / 256;

    k_zero<<<nbN, 256, 0, stream>>>(deg, N);
    k_count<<<nbE, 256, 0, stream>>>(dstp, deg, E);
    k_inv<<<nbN, 256, 0, stream>>>(deg, inv, N);
    k_scan1<<<nbN, 256, 0, stream>>>(deg, rowstart, blocksum, N);
    k_scan2<<<1, 256, 0, stream>>>(blocksum, nbN);
    k_scan3<<<nbN, 256, 0, stream>>>(rowstart, blocksum, cursor, N, E);
    k_fill<<<nbE, 256, 0, stream>>>(src, dstp, inv, cursor, ssrc, swv, E);

    k_gemm1<<<(N + 31) / 32, 256, 0, stream>>>(x, W1, h1, N);
    k_gather<128, true><<<(N + 3) / 4, 256, 0, stream>>>(h1, rowstart, ssrc, swv, inv, b1, act1, N);
    k_gemm2<<<(N + 63) / 64, 256, 0, stream>>>(act1, W2, h2, N);
    k_gather<64, false><<<(N + 3) / 4, 256, 0, stream>>>(h2, rowstart, ssrc, swv, inv, b2, out, N);
}